// Round 7
// baseline (238.516 us; speedup 1.0000x reference)
//
#include <hip/hip_runtime.h>

// Problem collapse: T=1, H=1, h0=c0=0 => Wh/f-gate dead; conv => pointwise
// matmul with Wx[(kh-1)//2,0,:,:]. 4 layers fused (split-bf16 MFMA,
// hi*hi+hi*lo+lo*hi ~ 2^-18 rel err), h4 emitted as split-bf16 planes.
// D1 GEMM split-bf16 MFMA (B gathered from global, no LDS), reduce + D2.

#define POS 131072
#define SH 72   // LDS row stride (shorts): 144 B = 16B-aligned; quad offset
                // 144 dwords = 16 mod 32 -> 2-way max (free) for u16 scatter

typedef __attribute__((ext_vector_type(8))) short bf16x8;
typedef __attribute__((ext_vector_type(4))) float f32x4;

__device__ __forceinline__ unsigned short f2bf_rn(float f) {
    unsigned u = __float_as_uint(f);
    u += 0x7FFF + ((u >> 16) & 1);
    return (unsigned short)(u >> 16);
}
__device__ __forceinline__ float bf2f(unsigned short h) {
    return __uint_as_float(((unsigned)h) << 16);
}
__device__ __forceinline__ float hsig(float x) {
    return fminf(fmaxf(fmaf(x, 0.2f, 0.5f), 0.0f), 1.0f);
}
__device__ __forceinline__ float tanh_e(float x) {
    float t = __expf(2.0f * x);
    return 1.0f - __fdividef(2.0f, t + 1.0f);
}

// Layer weights -> transposed split-bf16: per layer [hi:192x64][lo:192x64],
// row = g*64 + n. Grid 12 = 4 layers x 3 gates.
__global__ __launch_bounds__(256) void prep_w(
    const float* __restrict__ W1, const float* __restrict__ W2,
    const float* __restrict__ W3, const float* __restrict__ W4,
    unsigned short* __restrict__ WT)
{
    const int bid = blockIdx.x;
    const int ll = bid / 3;
    const int g  = bid - ll * 3;
    const float* W = (ll == 0) ? (W1 + 4 * 16384) :
                     (ll == 1) ? (W2 + 2 * 16384) :
                     (ll == 2) ? (W3 + 4 * 16384) : (W4 + 2 * 16384);
    const int gofs = (g == 0) ? 0 : ((g == 1) ? 128 : 192);
    unsigned short* hi = WT + ll * (2 * 192 * 64) + (g * 64) * 64;
    unsigned short* lo = hi + 192 * 64;
    const int n  = threadIdx.x & 63;
    const int c0 = threadIdx.x >> 6;
    #pragma unroll
    for (int cc = 0; cc < 16; cc++) {
        int c = cc * 4 + c0;
        float w = W[c * 256 + gofs + n];
        unsigned short h = f2bf_rn(w);
        hi[n * 64 + c] = h;
        lo[n * 64 + c] = f2bf_rn(w - bf2f(h));
    }
}

// Fused 4-layer gated pointwise stack, split-bf16 MFMA 16x16x32.
// Block = 32 positions (small state -> high occupancy), 4 waves; wave w owns
// output channels 16w..16w+15. B-frags loaded JIT from WT (L2-hot).
__global__ __launch_bounds__(256) void fused_mfma(
    const float* __restrict__ x,
    const unsigned short* __restrict__ WT,
    const float* __restrict__ B1, const float* __restrict__ B2,
    const float* __restrict__ B3, const float* __restrict__ B4,
    unsigned short* __restrict__ h4hi, unsigned short* __restrict__ h4lo)
{
    __shared__ unsigned short Hhi[32][SH];
    __shared__ unsigned short Hlo[32][SH];

    const int t = threadIdx.x;
    const int lane = t & 63;
    const int w = t >> 6;
    const int tx = lane & 15;
    const int quad = lane >> 4;
    const int n = 16 * w + tx;
    const int pbase = blockIdx.x * 32;

    // Stage x -> split-bf16 LDS (32 x 64).
    {
        const float4* xv = (const float4*)(x + (size_t)pbase * 64);
        #pragma unroll
        for (int k = 0; k < 2; k++) {
            int lin4 = t + k * 256;
            int p = lin4 >> 4;
            int c0 = (lin4 & 15) * 4;
            float4 v = xv[lin4];
            const float* vp = (const float*)&v;
            unsigned short h0 = f2bf_rn(vp[0]), h1 = f2bf_rn(vp[1]);
            unsigned short h2 = f2bf_rn(vp[2]), h3 = f2bf_rn(vp[3]);
            unsigned hh01 = (unsigned)h0 | ((unsigned)h1 << 16);
            unsigned hh23 = (unsigned)h2 | ((unsigned)h3 << 16);
            unsigned ll01 = (unsigned)f2bf_rn(vp[0] - bf2f(h0)) |
                            ((unsigned)f2bf_rn(vp[1] - bf2f(h1)) << 16);
            unsigned ll23 = (unsigned)f2bf_rn(vp[2] - bf2f(h2)) |
                            ((unsigned)f2bf_rn(vp[3] - bf2f(h3)) << 16);
            *(uint2*)&Hhi[p][c0] = make_uint2(hh01, hh23);
            *(uint2*)&Hlo[p][c0] = make_uint2(ll01, ll23);
        }
    }
    __syncthreads();

    #pragma unroll
    for (int l = 0; l < 4; l++) {
        const unsigned short* wl = WT + l * (2 * 192 * 64);
        const float* Bb = (l == 0) ? B1 : (l == 1) ? B2 : (l == 2) ? B3 : B4;
        const float bi = Bb[n];
        const float bg = Bb[128 + n];
        const float bo = Bb[192 + n];

        f32x4 acc[2][3];
        #pragma unroll
        for (int m = 0; m < 2; m++) {
            acc[m][0] = (f32x4){bi, bi, bi, bi};
            acc[m][1] = (f32x4){bg, bg, bg, bg};
            acc[m][2] = (f32x4){bo, bo, bo, bo};
        }

        #pragma unroll
        for (int ks = 0; ks < 2; ks++) {
            bf16x8 Bh[3], Bl[3];
            #pragma unroll
            for (int g = 0; g < 3; g++) {
                const unsigned short* bp = wl + (g * 64 + n) * 64 + ks * 32 + quad * 8;
                Bh[g] = *(const bf16x8*)bp;
                Bl[g] = *(const bf16x8*)(bp + 192 * 64);
            }
            #pragma unroll
            for (int m = 0; m < 2; m++) {
                bf16x8 Ah = *(const bf16x8*)&Hhi[m * 16 + tx][ks * 32 + quad * 8];
                bf16x8 Al = *(const bf16x8*)&Hlo[m * 16 + tx][ks * 32 + quad * 8];
                #pragma unroll
                for (int g = 0; g < 3; g++) {
                    acc[m][g] = __builtin_amdgcn_mfma_f32_16x16x32_bf16(Ah, Bh[g], acc[m][g], 0, 0, 0);
                    acc[m][g] = __builtin_amdgcn_mfma_f32_16x16x32_bf16(Ah, Bl[g], acc[m][g], 0, 0, 0);
                    acc[m][g] = __builtin_amdgcn_mfma_f32_16x16x32_bf16(Al, Bh[g], acc[m][g], 0, 0, 0);
                }
            }
        }

        // Epilogue compute in registers (no LDS access).
        float hv[2][4];
        #pragma unroll
        for (int m = 0; m < 2; m++)
            #pragma unroll
            for (int r = 0; r < 4; r++) {
                float cs = hsig(acc[m][0][r]) * tanh_e(acc[m][1][r]);
                hv[m][r] = hsig(acc[m][2][r]) * tanh_e(cs);
            }

        __syncthreads();   // all A-reads of Hhi/Hlo done -> safe to overwrite
        #pragma unroll
        for (int m = 0; m < 2; m++)
            #pragma unroll
            for (int r = 0; r < 4; r++) {
                int p = m * 16 + quad * 4 + r;
                unsigned short hh = f2bf_rn(hv[m][r]);
                Hhi[p][n] = hh;
                Hlo[p][n] = f2bf_rn(hv[m][r] - bf2f(hh));
            }
        __syncthreads();
    }

    // Coalesced copy-out: threads 0-127 write hi plane, 128-255 lo plane.
    // Each plane = 32 pos x 64 ch = 2048 shorts = 256 8-short chunks;
    // 128 threads x 2 iterations. (Round-6 bug: only 1 iteration = half tile.)
    {
        unsigned short* dstp = (t < 128) ? h4hi : h4lo;
        #pragma unroll
        for (int i = 0; i < 2; i++) {
            int idx = (t & 127) + i * 128;     // 0..255
            int p = idx >> 3;                  // 0..31
            int c0 = (idx & 7) * 8;
            const unsigned short* src = (t < 128) ? &Hhi[p][c0] : &Hlo[p][c0];
            *(uint4*)(dstp + (size_t)(pbase + p) * 64 + c0) = *(const uint4*)src;
        }
    }
}

// D1 partial GEMM, split-bf16 MFMA. Block = K-chunk of 128 (2 subs of 64).
// A (64 batches x K) staged in LDS; B = D1w gathered straight from global
// (each 256B row read exactly once per block) and split in registers.
__global__ __launch_bounds__(256) void d1_mfma(
    const unsigned short* __restrict__ Ahig, const unsigned short* __restrict__ Alog,
    const float* __restrict__ Bw, float* __restrict__ part)
{
    __shared__ unsigned short Ahi[64][SH], Alo[64][SH];
    const int t = threadIdx.x;
    const int kb = blockIdx.x;
    const int lane = t & 63, w = t >> 6;
    const int tx = lane & 15, quad = lane >> 4;
    const int n = 16 * w + tx;

    f32x4 acc[4];
    #pragma unroll
    for (int m = 0; m < 4; m++) acc[m] = (f32x4){0.0f, 0.0f, 0.0f, 0.0f};

    #pragma unroll
    for (int sub = 0; sub < 2; sub++) {
        const int k0 = kb * 128 + sub * 64;
        if (sub) __syncthreads();
        // Stage A planes (64 rows x 64 k shorts each).
        #pragma unroll
        for (int i = 0; i < 2; i++) {
            int lin8 = t + i * 256;
            int row = lin8 >> 3;
            int c0 = (lin8 & 7) * 8;
            size_t g = (size_t)row * 131072 + k0 + c0;
            *(uint4*)&Ahi[row][c0] = *(const uint4*)(Ahig + g);
            *(uint4*)&Alo[row][c0] = *(const uint4*)(Alog + g);
        }
        __syncthreads();

        #pragma unroll
        for (int ks = 0; ks < 2; ks++) {
            // B-frag: gather column n of D1w rows k0+ks*32+quad*8..+7, split.
            bf16x8 Bh, Bl;
            #pragma unroll
            for (int j = 0; j < 8; j++) {
                float bv = Bw[(size_t)(k0 + ks * 32 + quad * 8 + j) * 64 + n];
                unsigned short hb = f2bf_rn(bv);
                Bh[j] = (short)hb;
                Bl[j] = (short)f2bf_rn(bv - bf2f(hb));
            }
            #pragma unroll
            for (int m = 0; m < 4; m++) {
                bf16x8 Ah = *(const bf16x8*)&Ahi[m * 16 + tx][ks * 32 + quad * 8];
                bf16x8 Al = *(const bf16x8*)&Alo[m * 16 + tx][ks * 32 + quad * 8];
                acc[m] = __builtin_amdgcn_mfma_f32_16x16x32_bf16(Ah, Bh, acc[m], 0, 0, 0);
                acc[m] = __builtin_amdgcn_mfma_f32_16x16x32_bf16(Ah, Bl, acc[m], 0, 0, 0);
                acc[m] = __builtin_amdgcn_mfma_f32_16x16x32_bf16(Al, Bh, acc[m], 0, 0, 0);
            }
        }
    }

    float* dst = part + (size_t)kb * 4096;
    #pragma unroll
    for (int m = 0; m < 4; m++)
        #pragma unroll
        for (int r = 0; r < 4; r++)
            dst[(m * 16 + quad * 4 + r) * 64 + n] = acc[m][r];
}

// Reduce 1024 tiles + D1b, relu, dot D2w, + D2b. 64 blocks x 1024.
__global__ __launch_bounds__(1024) void d1_reduce(
    const float* __restrict__ part, const float* __restrict__ D1b,
    const float* __restrict__ D2w, const float* __restrict__ D2b,
    float* __restrict__ out)
{
    __shared__ float red[16][64];
    const int b = blockIdx.x;
    const int t = threadIdx.x;
    const int j = t & 63, s = t >> 6;
    float acc = 0.0f;
    #pragma unroll 4
    for (int m = 0; m < 64; m++)
        acc += part[(size_t)(s + 16 * m) * 4096 + b * 64 + j];
    red[s][j] = acc;
    __syncthreads();
    if (t < 64) {
        float v = D1b[t];
        #pragma unroll
        for (int s2 = 0; s2 < 16; s2++) v += red[s2][t];
        v = fmaxf(v, 0.0f) * D2w[t];
        #pragma unroll
        for (int off = 32; off > 0; off >>= 1)
            v += __shfl_down(v, off, 64);
        if (t == 0) out[b] = v + D2b[0];
    }
}

extern "C" void kernel_launch(void* const* d_in, const int* in_sizes, int n_in,
                              void* d_out, int out_size, void* d_ws, size_t ws_size,
                              hipStream_t stream) {
    (void)in_sizes; (void)n_in; (void)out_size; (void)ws_size;
    const float* x   = (const float*)d_in[0];
    const float* W1x = (const float*)d_in[1];
    const float* b1  = (const float*)d_in[3];
    const float* W2x = (const float*)d_in[4];
    const float* b2  = (const float*)d_in[6];
    const float* W3x = (const float*)d_in[7];
    const float* b3  = (const float*)d_in[9];
    const float* W4x = (const float*)d_in[10];
    const float* b4  = (const float*)d_in[12];
    const float* D1w = (const float*)d_in[13];
    const float* D1b = (const float*)d_in[14];
    const float* D2w = (const float*)d_in[15];
    const float* D2b = (const float*)d_in[16];
    float* out = (float*)d_out;

    unsigned short* h4hi = (unsigned short*)d_ws;            // 16.8 MB
    unsigned short* h4lo = h4hi + (size_t)POS * 64;          // 16.8 MB
    float* part = (float*)(h4lo + (size_t)POS * 64);         // 1024*4096*4 = 16.8 MB
    unsigned short* WT = (unsigned short*)(part + (size_t)1024 * 4096);  // 384 KB

    prep_w<<<dim3(12), dim3(256), 0, stream>>>(W1x, W2x, W3x, W4x, WT);
    fused_mfma<<<dim3(POS / 32), dim3(256), 0, stream>>>(
        x, WT, b1, b2, b3, b4, h4hi, h4lo);
    d1_mfma<<<dim3(1024), dim3(256), 0, stream>>>(h4hi, h4lo, D1w, part);
    d1_reduce<<<dim3(64), dim3(1024), 0, stream>>>(part, D1b, D2w, D2b, out);
}